// Round 18
// baseline (381.293 us; speedup 1.0000x reference)
//
#include <hip/hip_runtime.h>
#include <hip/hip_bf16.h>

constexpr int N_NODES = 50000;
constexpr int N_EDGES = 800000;
constexpr int F_IN = 128;
constexpr int H1 = 64;
constexpr int HEADS = 4;
constexpr int D_H = 32;
constexpr int HOUT = HEADS * D_H;       // 128
constexpr int N_REL = 4;
constexpr int N_GRAPHS = 64;
constexpr int MBIG = H1 * (1 + N_REL);  // 320
constexpr int NBLK = (N_NODES + 255) / 256;  // 196
constexpr int N_PAD = 50048;            // 64 * 782

typedef __attribute__((ext_vector_type(8))) short bf16x8;
typedef __attribute__((ext_vector_type(4))) float f32x4;

// ---- monotonic float<->uint for atomicMax on floats ----
__device__ __forceinline__ unsigned f2mono(float f) {
  unsigned u = __float_as_uint(f);
  return (u & 0x80000000u) ? ~u : (u | 0x80000000u);
}
__device__ __forceinline__ float mono2f(unsigned m) {
  unsigned u = (m & 0x80000000u) ? (m & 0x7FFFFFFFu) : ~m;
  return __uint_as_float(u);
}
constexpr unsigned MONO_NEG_INF = 0x007FFFFFu;

// ---- bf16 helpers ----
__device__ __forceinline__ unsigned short f2bf(float f) {
  unsigned u = __float_as_uint(f);
  unsigned r = (u + 0x7FFFu + ((u >> 16) & 1u)) >> 16;  // RNE
  return (unsigned short)r;
}
__device__ __forceinline__ float bf2f(unsigned short h) {
  return __uint_as_float((unsigned)h << 16);
}
__device__ __forceinline__ float bflo(unsigned u) { return __uint_as_float(u << 16); }
__device__ __forceinline__ float bfhi(unsigned u) { return __uint_as_float(u & 0xFFFF0000u); }

// ======= fused prep: hist | build_wT | init_mono | watt =======
constexpr int HIST_BLOCKS = (N_EDGES + 255) / 256;               // 3125
constexpr int WT_BLOCKS = (MBIG * F_IN + HOUT * H1 + 255) / 256; // 192

__global__ __launch_bounds__(256) void pre_fused(
    const float* __restrict__ W_root, const float* __restrict__ W_rel,
    const float* __restrict__ W_gat,
    const float* __restrict__ att_src, const float* __restrict__ att_dst,
    const int* __restrict__ dst,
    unsigned short* __restrict__ WbT_hi, unsigned short* __restrict__ WbT_lo,
    unsigned short* __restrict__ WgT_hi, unsigned short* __restrict__ WgT_lo,
    int* __restrict__ deg, int* __restrict__ rank,
    unsigned* __restrict__ pm,
    float* __restrict__ was, float* __restrict__ wad) {
  int b = blockIdx.x;
  if (b < HIST_BLOCKS) {
    int e = b * 256 + threadIdx.x;
    if (e < N_EDGES) rank[e] = atomicAdd(&deg[dst[e]], 1);
  } else if (b < HIST_BLOCKS + WT_BLOCKS) {
    int i = (b - HIST_BLOCKS) * 256 + threadIdx.x;
    if (i < MBIG * F_IN) {
      int c = i / F_IN, k = i % F_IN;
      float w = (c < H1) ? W_root[k * H1 + c]
                         : W_rel[((size_t)(((c - H1) >> 6) * F_IN + k)) * H1 + ((c - H1) & 63)];
      unsigned short hi = f2bf(w);
      WbT_hi[i] = hi;
      WbT_lo[i] = f2bf(w - bf2f(hi));
    } else {
      int j = i - MBIG * F_IN;
      if (j < HOUT * H1) {
        int c = j / H1, k = j % H1;
        float w = W_gat[k * HOUT + c];
        unsigned short hi = f2bf(w);
        WgT_hi[j] = hi;
        WgT_lo[j] = f2bf(w - bf2f(hi));
      }
    }
  } else if (b == HIST_BLOCKS + WT_BLOCKS) {
    for (int i = threadIdx.x; i < N_GRAPHS * 16; i += 256) pm[i] = MONO_NEG_INF;
  } else {
    // watt: was/wad[k*4+hh] = sum_d W_gat[k][hh*32+d] * att[hh][d]
    int t = threadIdx.x;          // t = k*4 + hh, 256 threads exactly
    int k = t >> 2, hh = t & 3;
    float s = 0.f, d2 = 0.f;
#pragma unroll 8
    for (int dd = 0; dd < D_H; ++dd) {
      float wg = W_gat[k * HOUT + hh * D_H + dd];
      s += wg * att_src[hh * D_H + dd];
      d2 += wg * att_dst[hh * D_H + dd];
    }
    was[t] = s;
    wad[t] = d2;
  }
}

// ============ gemm1 body: K=128, f32 A, async double-buffered chunks ======
__device__ __forceinline__ void gemm_body128(int bx, int by,
    const float* __restrict__ Af,
    const unsigned short* __restrict__ BT_hi,
    const unsigned short* __restrict__ BT_lo,
    unsigned short* __restrict__ Cbf, int N, int M) {
  constexpr int K = 128, KC = 64;
  __shared__ unsigned short Ah[64 * KC];
  __shared__ unsigned short Al[64 * KC];
  const int tid = threadIdx.x;
  const int rowBase = bx * 64;
  const int colBase = by * 64;
  const int wv = tid >> 6, lane = tid & 63;
  const int wr = (wv >> 1) * 32, wc = (wv & 1) * 32;
  const int lrow = lane & 15, lkc = lane >> 4;
  int r_[4], c4_[4];
#pragma unroll
  for (int it = 0; it < 4; ++it) {
    int s = it * 256 + tid;
    r_[it] = s >> 4;
    c4_[it] = (s & 15) * 4;
  }
  f32x4 acc[2][2] = {};
#pragma unroll
  for (int it = 0; it < 4; ++it) {
    int gr = rowBase + r_[it];
    float4 v = make_float4(0.f, 0.f, 0.f, 0.f);
    if (gr < N) v = *reinterpret_cast<const float4*>(&Af[(size_t)gr * K + c4_[it]]);
    ushort4 hi, lo;
    hi.x = f2bf(v.x); lo.x = f2bf(v.x - bf2f(hi.x));
    hi.y = f2bf(v.y); lo.y = f2bf(v.y - bf2f(hi.y));
    hi.z = f2bf(v.z); lo.z = f2bf(v.z - bf2f(hi.z));
    hi.w = f2bf(v.w); lo.w = f2bf(v.w - bf2f(hi.w));
    int sw = c4_[it] ^ ((r_[it] & 7) << 3);
    *reinterpret_cast<ushort4*>(&Ah[r_[it] * KC + sw]) = hi;
    *reinterpret_cast<ushort4*>(&Al[r_[it] * KC + sw]) = lo;
  }
  __syncthreads();
  float4 v1[4];
#pragma unroll
  for (int it = 0; it < 4; ++it) {
    int gr = rowBase + r_[it];
    v1[it] = make_float4(0.f, 0.f, 0.f, 0.f);
    if (gr < N) v1[it] = *reinterpret_cast<const float4*>(&Af[(size_t)gr * K + KC + c4_[it]]);
  }
#pragma unroll
  for (int ch = 0; ch < 2; ++ch) {
    if (ch == 1) {
      __syncthreads();
#pragma unroll
      for (int it = 0; it < 4; ++it) {
        float4 v = v1[it];
        ushort4 hi, lo;
        hi.x = f2bf(v.x); lo.x = f2bf(v.x - bf2f(hi.x));
        hi.y = f2bf(v.y); lo.y = f2bf(v.y - bf2f(hi.y));
        hi.z = f2bf(v.z); lo.z = f2bf(v.z - bf2f(hi.z));
        hi.w = f2bf(v.w); lo.w = f2bf(v.w - bf2f(hi.w));
        int sw = c4_[it] ^ ((r_[it] & 7) << 3);
        *reinterpret_cast<ushort4*>(&Ah[r_[it] * KC + sw]) = hi;
        *reinterpret_cast<ushort4*>(&Al[r_[it] * KC + sw]) = lo;
      }
      __syncthreads();
    }
#pragma unroll
    for (int ks = 0; ks < KC; ks += 32) {
      bf16x8 ah[2], al[2], bh[2], bl[2];
#pragma unroll
      for (int fr = 0; fr < 2; ++fr) {
        int r = wr + fr * 16 + lrow;
        int sw = (ks + lkc * 8) ^ ((r & 7) << 3);
        ah[fr] = *reinterpret_cast<const bf16x8*>(&Ah[r * KC + sw]);
        al[fr] = *reinterpret_cast<const bf16x8*>(&Al[r * KC + sw]);
      }
#pragma unroll
      for (int fc = 0; fc < 2; ++fc) {
        int c = colBase + wc + fc * 16 + lrow;
        bh[fc] = *reinterpret_cast<const bf16x8*>(&BT_hi[(size_t)c * K + ch * KC + ks + lkc * 8]);
        bl[fc] = *reinterpret_cast<const bf16x8*>(&BT_lo[(size_t)c * K + ch * KC + ks + lkc * 8]);
      }
#pragma unroll
      for (int fr = 0; fr < 2; ++fr)
#pragma unroll
        for (int fc = 0; fc < 2; ++fc) {
          acc[fr][fc] = __builtin_amdgcn_mfma_f32_16x16x32_bf16(ah[fr], bh[fc], acc[fr][fc], 0, 0, 0);
          acc[fr][fc] = __builtin_amdgcn_mfma_f32_16x16x32_bf16(ah[fr], bl[fc], acc[fr][fc], 0, 0, 0);
          acc[fr][fc] = __builtin_amdgcn_mfma_f32_16x16x32_bf16(al[fr], bh[fc], acc[fr][fc], 0, 0, 0);
        }
    }
  }
#pragma unroll
  for (int fr = 0; fr < 2; ++fr) {
#pragma unroll
    for (int i = 0; i < 4; ++i) {
      int row = rowBase + wr + fr * 16 + lkc * 4 + i;
      if (row < N) {
#pragma unroll
        for (int fc = 0; fc < 2; ++fc) {
          int col = colBase + wc + fc * 16 + lrow;
          Cbf[(size_t)row * M + col] = f2bf(acc[fr][fc][i]);
        }
      }
    }
  }
}

// ---- gemm1 (xt from f32 x) fused with CSR fill; XCD-group swizzle ----
constexpr int G1_BX = N_PAD / 64;          // 782
constexpr int G1_GRID = 3920;              // 8 * 5 * 98
__global__ __launch_bounds__(256) void gemm1_fill(
    const float* __restrict__ x,
    const unsigned short* __restrict__ wbt_hi, const unsigned short* __restrict__ wbt_lo,
    unsigned short* __restrict__ xtbf,
    const int* __restrict__ src, const int* __restrict__ dst,
    const int* __restrict__ etype, const int* __restrict__ off,
    const int* __restrict__ rank, int* __restrict__ eprep) {
  if (blockIdx.x < G1_GRID) {
    int b = blockIdx.x;
    int r8 = b & 7, s = b >> 3;
    int by = s % 5, q = s / 5;
    int bx = q * 8 + r8;
    if (bx < G1_BX)
      gemm_body128(bx, by, x, wbt_hi, wbt_lo, xtbf, N_NODES, MBIG);
  } else {
    int e = (blockIdx.x - G1_GRID) * 256 + threadIdx.x;
    if (e < N_EDGES) {
      int pos = off[dst[e]] + rank[e];
      eprep[pos] = src[e] | (etype[e] << 16);
    }
  }
}

// ---- scan stage 1: per-block sums ----
__global__ __launch_bounds__(256) void k_s1(const int* __restrict__ deg,
                                            int* __restrict__ bsum) {
  __shared__ int ss[256];
  int t = threadIdx.x;
  int i = blockIdx.x * 256 + t;
  ss[t] = (i < N_NODES) ? deg[i] : 0;
  __syncthreads();
  for (int d = 128; d > 0; d >>= 1) {
    if (t < d) ss[t] += ss[t + d];
    __syncthreads();
  }
  if (t == 0) bsum[blockIdx.x] = ss[0];
}

// ---- scan stage 2: exclusive scan of block sums ----
__global__ __launch_bounds__(256) void k_s2(const int* __restrict__ bsum,
                                            int* __restrict__ bbase,
                                            int* __restrict__ off) {
  __shared__ int ss[256];
  int t = threadIdx.x;
  int v = (t < NBLK) ? bsum[t] : 0;
  ss[t] = v;
  __syncthreads();
  for (int d = 1; d < 256; d <<= 1) {
    int u = (t >= d) ? ss[t - d] : 0;
    __syncthreads();
    ss[t] += u;
    __syncthreads();
  }
  if (t < NBLK) bbase[t] = ss[t] - v;
  if (t == NBLK - 1) off[N_NODES] = ss[t];
}

// ---- scan stage 3: block-local scan + base ----
__global__ __launch_bounds__(256) void k_s3(const int* __restrict__ deg,
                                            const int* __restrict__ bbase,
                                            int* __restrict__ off) {
  __shared__ int ss[256];
  int t = threadIdx.x;
  int i = blockIdx.x * 256 + t;
  int v = (i < N_NODES) ? deg[i] : 0;
  ss[t] = v;
  __syncthreads();
  for (int d = 1; d < 256; d <<= 1) {
    int u = (t >= d) ? ss[t - d] : 0;
    __syncthreads();
    ss[t] += u;
    __syncthreads();
  }
  if (i < N_NODES) off[i] = bbase[blockIdx.x] + ss[t] - v;
}

// ---- RGCN: gather from bf16 xt; wave/node; computes h in-register, then
//      FUSED: a_s/a_d = h @ (W_gat @ att)  AND  g = h @ W_gat (bf16 out).
//      gemm2 eliminated. ----
__global__ __launch_bounds__(256) void rgcn_gather(const unsigned short* __restrict__ xtbf,
                                                   const int* __restrict__ off,
                                                   const int* __restrict__ eprep,
                                                   const float* __restrict__ b_rgcn,
                                                   const float* __restrict__ was,
                                                   const float* __restrict__ wad,
                                                   const unsigned short* __restrict__ wgt_hi,
                                                   const unsigned short* __restrict__ wgt_lo,
                                                   unsigned short* __restrict__ gbf,
                                                   float* __restrict__ a_s,
                                                   float* __restrict__ a_d) {
  __shared__ float h_lds[4][H1];
  int wid = (blockIdx.x * 256 + threadIdx.x) >> 6;
  int wv = threadIdx.x >> 6;
  int lane = threadIdx.x & 63;
  int half = lane >> 5;
  int cp = lane & 31;
  int start = off[wid], end = off[wid + 1];
  float a0x=0.f,a0y=0.f,a1x=0.f,a1y=0.f,a2x=0.f,a2y=0.f,a3x=0.f,a3y=0.f;
  int c0=0,c1=0,c2=0,c3=0;
  int niter = (end - start + 1) >> 1;
  for (int t = 0; t < niter; t += 2) {
    int idx0 = start + 2 * t + half;
    int idx1 = idx0 + 2;
    int p0 = (idx0 < end) ? eprep[idx0] : 0x70000;
    int p1 = (idx1 < end) ? eprep[idx1] : 0x70000;
    int s0 = p0 & 0xFFFF, r0 = p0 >> 16;
    int s1 = p1 & 0xFFFF, r1 = p1 >> 16;
    unsigned u0 = *reinterpret_cast<const unsigned*>(
        &xtbf[(size_t)s0 * MBIG + H1 + (r0 << 6) + cp * 2]);
    unsigned u1 = *reinterpret_cast<const unsigned*>(
        &xtbf[(size_t)s1 * MBIG + H1 + (r1 << 6) + cp * 2]);
    float v0x = bflo(u0), v0y = bfhi(u0);
    float v1x = bflo(u1), v1y = bfhi(u1);
    a0x += (r0==0)?v0x:0.f; a0y += (r0==0)?v0y:0.f; c0 += (r0==0);
    a1x += (r0==1)?v0x:0.f; a1y += (r0==1)?v0y:0.f; c1 += (r0==1);
    a2x += (r0==2)?v0x:0.f; a2y += (r0==2)?v0y:0.f; c2 += (r0==2);
    a3x += (r0==3)?v0x:0.f; a3y += (r0==3)?v0y:0.f; c3 += (r0==3);
    a0x += (r1==0)?v1x:0.f; a0y += (r1==0)?v1y:0.f; c0 += (r1==0);
    a1x += (r1==1)?v1x:0.f; a1y += (r1==1)?v1y:0.f; c1 += (r1==1);
    a2x += (r1==2)?v1x:0.f; a2y += (r1==2)?v1y:0.f; c2 += (r1==2);
    a3x += (r1==3)?v1x:0.f; a3y += (r1==3)?v1y:0.f; c3 += (r1==3);
  }
  a0x += __shfl_xor(a0x, 32); a0y += __shfl_xor(a0y, 32);
  a1x += __shfl_xor(a1x, 32); a1y += __shfl_xor(a1y, 32);
  a2x += __shfl_xor(a2x, 32); a2y += __shfl_xor(a2y, 32);
  a3x += __shfl_xor(a3x, 32); a3y += __shfl_xor(a3y, 32);
  c0 += __shfl_xor(c0, 32); c1 += __shfl_xor(c1, 32);
  c2 += __shfl_xor(c2, 32); c3 += __shfl_xor(c3, 32);
  if (half == 0) {
    unsigned ur = *reinterpret_cast<const unsigned*>(&xtbf[(size_t)wid * MBIG + cp * 2]);
    float2 bb = *reinterpret_cast<const float2*>(&b_rgcn[cp * 2]);
    float i0 = 1.0f / (float)max(c0, 1);
    float i1 = 1.0f / (float)max(c1, 1);
    float i2 = 1.0f / (float)max(c2, 1);
    float i3 = 1.0f / (float)max(c3, 1);
    float vx = bflo(ur) + bb.x + a0x * i0 + a1x * i1 + a2x * i2 + a3x * i3;
    float vy = bfhi(ur) + bb.y + a0y * i0 + a1y * i1 + a2y * i2 + a3y * i3;
    vx = fmaxf(vx, 0.f);
    vy = fmaxf(vy, 0.f);
    h_lds[wv][cp * 2] = vx;
    h_lds[wv][cp * 2 + 1] = vy;
    // ---- attention coefficients: a = h @ was / h @ wad ----
    float4 wsA = *reinterpret_cast<const float4*>(&was[cp * 8]);      // k=2cp
    float4 wsB = *reinterpret_cast<const float4*>(&was[cp * 8 + 4]);  // k=2cp+1
    float4 wdA = *reinterpret_cast<const float4*>(&wad[cp * 8]);
    float4 wdB = *reinterpret_cast<const float4*>(&wad[cp * 8 + 4]);
    float ps0 = vx * wsA.x + vy * wsB.x;
    float ps1 = vx * wsA.y + vy * wsB.y;
    float ps2 = vx * wsA.z + vy * wsB.z;
    float ps3 = vx * wsA.w + vy * wsB.w;
    float pd0 = vx * wdA.x + vy * wdB.x;
    float pd1 = vx * wdA.y + vy * wdB.y;
    float pd2 = vx * wdA.z + vy * wdB.z;
    float pd3 = vx * wdA.w + vy * wdB.w;
#pragma unroll
    for (int d = 1; d < 32; d <<= 1) {
      ps0 += __shfl_xor(ps0, d); ps1 += __shfl_xor(ps1, d);
      ps2 += __shfl_xor(ps2, d); ps3 += __shfl_xor(ps3, d);
      pd0 += __shfl_xor(pd0, d); pd1 += __shfl_xor(pd1, d);
      pd2 += __shfl_xor(pd2, d); pd3 += __shfl_xor(pd3, d);
    }
    if (cp == 0) {
      *reinterpret_cast<float4*>(&a_s[(size_t)wid * 4]) = make_float4(ps0, ps1, ps2, ps3);
      *reinterpret_cast<float4*>(&a_d[(size_t)wid * 4]) = make_float4(pd0, pd1, pd2, pd3);
    }
  }
  __syncthreads();
  // ---- fused gemm2: g[c] = sum_k h[k] * W_gat[k][c], c = 2*lane, 2*lane+1
  const unsigned short* wh0 = wgt_hi + (size_t)(2 * lane) * H1;
  const unsigned short* wl0 = wgt_lo + (size_t)(2 * lane) * H1;
  const unsigned short* wh1 = wh0 + H1;
  const unsigned short* wl1 = wl0 + H1;
  float g0 = 0.f, g1 = 0.f;
#pragma unroll
  for (int k4 = 0; k4 < H1; k4 += 4) {
    ushort4 h0 = *reinterpret_cast<const ushort4*>(wh0 + k4);
    ushort4 l0 = *reinterpret_cast<const ushort4*>(wl0 + k4);
    ushort4 h1v = *reinterpret_cast<const ushort4*>(wh1 + k4);
    ushort4 l1v = *reinterpret_cast<const ushort4*>(wl1 + k4);
    float hk0 = h_lds[wv][k4 + 0];
    float hk1 = h_lds[wv][k4 + 1];
    float hk2 = h_lds[wv][k4 + 2];
    float hk3 = h_lds[wv][k4 + 3];
    g0 += hk0 * (bf2f(h0.x) + bf2f(l0.x)) + hk1 * (bf2f(h0.y) + bf2f(l0.y))
        + hk2 * (bf2f(h0.z) + bf2f(l0.z)) + hk3 * (bf2f(h0.w) + bf2f(l0.w));
    g1 += hk0 * (bf2f(h1v.x) + bf2f(l1v.x)) + hk1 * (bf2f(h1v.y) + bf2f(l1v.y))
        + hk2 * (bf2f(h1v.z) + bf2f(l1v.z)) + hk3 * (bf2f(h1v.w) + bf2f(l1v.w));
  }
  unsigned gp = (unsigned)f2bf(g0) | ((unsigned)f2bf(g1) << 16);
  *reinterpret_cast<unsigned*>(&gbf[(size_t)wid * HOUT + lane * 2]) = gp;
}

// ---- GAT + head fused ----
constexpr int GAT_BLOCKS = 2048;
constexpr int GAT_WAVES = GAT_BLOCKS * 4;   // 8192
__global__ __launch_bounds__(256) void gat_fused(const unsigned short* __restrict__ gbf,
                                                 const float* __restrict__ a_s,
                                                 const float* __restrict__ a_d,
                                                 const int* __restrict__ off,
                                                 const int* __restrict__ eprep,
                                                 const float* __restrict__ b_gat,
                                                 const float* __restrict__ W1,
                                                 const float* __restrict__ b1,
                                                 const int* __restrict__ batch,
                                                 unsigned* __restrict__ p_mono) {
  __shared__ float w1s[HOUT * 16];        // W1[k][j]
  __shared__ float ob[4][HOUT];           // per-wave o row
  __shared__ unsigned sp[N_GRAPHS * 16];
  const int t = threadIdx.x;
  for (int i = t; i < HOUT * 16; i += 256) w1s[i] = W1[i];
  for (int i = t; i < N_GRAPHS * 16; i += 256) sp[i] = MONO_NEG_INF;
  __syncthreads();
  const int wv = t >> 6, lane = t & 63;
  const int hh = lane >> 4;
  const int jj = lane & 15, grp = lane >> 4;
  const int w = blockIdx.x * 4 + wv;
  const int q = N_NODES / GAT_WAVES;
  const int r = N_NODES % GAT_WAVES;
  const int nbeg = w * q + ((w < r) ? w : r);
  const int ncnt = q + ((w < r) ? 1 : 0);
  for (int wid = nbeg; wid < nbeg + ncnt; ++wid) {
    int start = off[wid], end = off[wid + 1];
    float4 ad4 = *reinterpret_cast<const float4*>(a_d + (size_t)wid * 4);
    float adh = (hh == 0) ? ad4.x : (hh == 1) ? ad4.y : (hh == 2) ? ad4.z : ad4.w;
    float ox = 0.f, oy = 0.f, den = 0.f;
    int i = start;
    for (; i + 4 <= end; i += 4) {
      int p0 = eprep[i], p1 = eprep[i + 1], p2 = eprep[i + 2], p3 = eprep[i + 3];
      int s0 = p0 & 0xFFFF, s1 = p1 & 0xFFFF, s2 = p2 & 0xFFFF, s3 = p3 & 0xFFFF;
      float as0 = a_s[(size_t)s0 * 4 + hh];
      float as1 = a_s[(size_t)s1 * 4 + hh];
      float as2 = a_s[(size_t)s2 * 4 + hh];
      float as3 = a_s[(size_t)s3 * 4 + hh];
      unsigned u0 = *reinterpret_cast<const unsigned*>(&gbf[(size_t)s0 * HOUT + lane * 2]);
      unsigned u1 = *reinterpret_cast<const unsigned*>(&gbf[(size_t)s1 * HOUT + lane * 2]);
      unsigned u2 = *reinterpret_cast<const unsigned*>(&gbf[(size_t)s2 * HOUT + lane * 2]);
      unsigned u3 = *reinterpret_cast<const unsigned*>(&gbf[(size_t)s3 * HOUT + lane * 2]);
      float e0 = as0 + adh; e0 = (e0 > 0.f) ? e0 : 0.2f * e0;
      float e1 = as1 + adh; e1 = (e1 > 0.f) ? e1 : 0.2f * e1;
      float e2 = as2 + adh; e2 = (e2 > 0.f) ? e2 : 0.2f * e2;
      float e3 = as3 + adh; e3 = (e3 > 0.f) ? e3 : 0.2f * e3;
      float x0 = __expf(e0), x1 = __expf(e1), x2 = __expf(e2), x3 = __expf(e3);
      den += x0 + x1 + x2 + x3;
      ox += x0 * bflo(u0) + x1 * bflo(u1) + x2 * bflo(u2) + x3 * bflo(u3);
      oy += x0 * bfhi(u0) + x1 * bfhi(u1) + x2 * bfhi(u2) + x3 * bfhi(u3);
    }
    for (; i < end; ++i) {
      int p = eprep[i];
      int s = p & 0xFFFF;
      float as = a_s[(size_t)s * 4 + hh];
      unsigned u = *reinterpret_cast<const unsigned*>(&gbf[(size_t)s * HOUT + lane * 2]);
      float e = as + adh; e = (e > 0.f) ? e : 0.2f * e;
      float ex = __expf(e);
      den += ex;
      ox += ex * bflo(u);
      oy += ex * bfhi(u);
    }
    float dinv = (den > 0.f) ? (1.0f / den) : 0.f;
    float2 bg = *reinterpret_cast<const float2*>(b_gat + lane * 2);
    float vx = ox * dinv + bg.x; vx = (vx > 0.f) ? vx : 0.01f * vx;
    float vy = oy * dinv + bg.y; vy = (vy > 0.f) ? vy : 0.01f * vy;
    *reinterpret_cast<float2*>(&ob[wv][lane * 2]) = make_float2(vx, vy);
    float acc = 0.f;
#pragma unroll 8
    for (int i2 = 0; i2 < 32; ++i2) {
      int c = grp + 4 * i2;
      acc += ob[wv][c] * w1s[c * 16 + jj];
    }
    acc += __shfl_xor(acc, 16);
    acc += __shfl_xor(acc, 32);
    float z = acc + b1[jj];
    z = (z > 0.f) ? z : 0.01f * z;
    int b = batch[wid];
    if (lane < 16) atomicMax(&sp[b * 16 + jj], f2mono(z));
  }
  __syncthreads();
  for (int i = t; i < N_GRAPHS * 16; i += 256) {
    unsigned v = sp[i];
    if (v != MONO_NEG_INF) atomicMax(p_mono + i, v);
  }
}

// ---- y = p @ W2 + b2 ----
__global__ void final_y(const unsigned* __restrict__ p_mono,
                        const float* __restrict__ W2,
                        const float* __restrict__ b2,
                        float* __restrict__ y) {
  int gr = threadIdx.x;
  if (gr >= N_GRAPHS) return;
  float acc = b2[0];
#pragma unroll
  for (int k = 0; k < 16; ++k) acc += mono2f(p_mono[gr * 16 + k]) * W2[k];
  y[gr] = acc;
}

extern "C" void kernel_launch(void* const* d_in, const int* in_sizes, int n_in,
                              void* d_out, int out_size, void* d_ws, size_t ws_size,
                              hipStream_t stream) {
  const float* x       = (const float*)d_in[0];
  const int*   eidx    = (const int*)d_in[1];
  const int*   etype   = (const int*)d_in[2];
  const int*   batch   = (const int*)d_in[3];
  const float* W_rel   = (const float*)d_in[4];
  const float* W_root  = (const float*)d_in[5];
  const float* b_rgcn  = (const float*)d_in[6];
  const float* W_gat   = (const float*)d_in[7];
  const float* att_src = (const float*)d_in[8];
  const float* att_dst = (const float*)d_in[9];
  const float* b_gat   = (const float*)d_in[10];
  const float* W1      = (const float*)d_in[11];
  const float* b1      = (const float*)d_in[12];
  const float* W2      = (const float*)d_in[13];
  const float* b2      = (const float*)d_in[14];
  float* y = (float*)d_out;

  const int* src = eidx;
  const int* dst = eidx + N_EDGES;

  float* ws = (float*)d_ws;
  // ---- workspace layout (float offsets) ----
  const size_t OFF_XTBF= 0;           //  8,007,680 f: xt bf16 [N_PAD,320]
  const size_t OFF_GBF = 8007680;     //  3,203,072 f: g bf16 [N_PAD,128] (own region!)
  const size_t OFF_AS  = 11210752;    //    200,000  a_src
  const size_t OFF_AD  = 11410752;    //    200,000  a_dst
  const size_t OFF_PM  = 11610752;    //      1,024 f = 1024 u32 pool max
  const size_t OFF_DEG = 11611776;    //     50,000  deg (int)
  const size_t OFF_OFFS= 11661776;    //     50,001  off (int)
  const size_t OFF_RANK= 11711780;    //    800,000  rank (int)
  const size_t OFF_EP  = 12511780;    //    800,000  eprep (int)
  const size_t OFF_BS  = 13311780;    //        196
  const size_t OFF_BB  = 13311976;    //        196
  const size_t OFF_WAS = 13312176;    //        256  was (16B aligned)
  const size_t OFF_WAD = 13312432;    //        256  wad
  const size_t OFF_WBH = 13312688;    //     20,480  WbigT_hi (16B aligned)
  const size_t OFF_WBL = 13333168;    //     20,480  WbigT_lo
  const size_t OFF_WGH = 13353648;    //      4,096  WgatT_hi
  const size_t OFF_WGL = 13357744;    //      4,096  WgatT_lo
  const size_t TOTAL_F = 13361840;
  if (ws_size < TOTAL_F * sizeof(float)) return;

  unsigned short* xtbf = (unsigned short*)(ws + OFF_XTBF);
  unsigned short* gbf  = (unsigned short*)(ws + OFF_GBF);
  float* a_s   = ws + OFF_AS;
  float* a_d   = ws + OFF_AD;
  unsigned* pm = (unsigned*)(ws + OFF_PM);
  int* deg     = (int*)(ws + OFF_DEG);
  int* offs    = (int*)(ws + OFF_OFFS);
  int* rank    = (int*)(ws + OFF_RANK);
  int* eprep   = (int*)(ws + OFF_EP);
  int* bsum    = (int*)(ws + OFF_BS);
  int* bbase   = (int*)(ws + OFF_BB);
  float* was   = ws + OFF_WAS;
  float* wad   = ws + OFF_WAD;
  unsigned short* wbt_hi = (unsigned short*)(ws + OFF_WBH);
  unsigned short* wbt_lo = (unsigned short*)(ws + OFF_WBL);
  unsigned short* wgt_hi = (unsigned short*)(ws + OFF_WGH);
  unsigned short* wgt_lo = (unsigned short*)(ws + OFF_WGL);

  // 1. deg = 0 (before fused hist)
  hipMemsetAsync(deg, 0, N_NODES * sizeof(int), stream);

  // 2. fused prep: hist(+rank) | build_wT | init_mono | watt
  pre_fused<<<HIST_BLOCKS + WT_BLOCKS + 2, 256, 0, stream>>>(
      W_root, W_rel, W_gat, att_src, att_dst, dst,
      wbt_hi, wbt_lo, wgt_hi, wgt_lo, deg, rank, pm, was, wad);

  // 3. scan (off from deg)
  k_s1<<<NBLK, 256, 0, stream>>>(deg, bsum);
  k_s2<<<1, 256, 0, stream>>>(bsum, bbase, offs);
  k_s3<<<NBLK, 256, 0, stream>>>(deg, bbase, offs);

  // 4. gemm1 (XCD-swizzled, async dbuf chunks) fused with CSR fill
  gemm1_fill<<<G1_GRID + HIST_BLOCKS, 256, 0, stream>>>(
      x, wbt_hi, wbt_lo, xtbf, src, dst, etype, offs, rank, eprep);

  // 5. RGCN gather -> h (regs) + fused a_s/a_d + fused g (bf16)
  rgcn_gather<<<N_NODES / 4, 256, 0, stream>>>(xtbf, offs, eprep, b_rgcn,
                                               was, wad, wgt_hi, wgt_lo,
                                               gbf, a_s, a_d);

  // 6. fused GAT aggregation + head + per-graph max pool
  gat_fused<<<GAT_BLOCKS, 256, 0, stream>>>(gbf, a_s, a_d, offs, eprep, b_gat,
                                            W1, b1, batch, pm);

  // 7. y = p @ W2 + b2
  final_y<<<1, 64, 0, stream>>>(pm, W2, b2, y);
}

// Round 19
// 265.723 us; speedup vs baseline: 1.4349x; 1.4349x over previous
//
#include <hip/hip_runtime.h>
#include <hip/hip_bf16.h>

constexpr int N_NODES = 50000;
constexpr int N_EDGES = 800000;
constexpr int F_IN = 128;
constexpr int H1 = 64;
constexpr int HEADS = 4;
constexpr int D_H = 32;
constexpr int HOUT = HEADS * D_H;       // 128
constexpr int N_REL = 4;
constexpr int N_GRAPHS = 64;
constexpr int MBIG = H1 * (1 + N_REL);  // 320
constexpr int NBLK = (N_NODES + 255) / 256;  // 196
constexpr int N_PAD = 50048;            // 64 * 782

typedef __attribute__((ext_vector_type(8))) short bf16x8;
typedef __attribute__((ext_vector_type(4))) float f32x4;

// ---- monotonic float<->uint for atomicMax on floats ----
__device__ __forceinline__ unsigned f2mono(float f) {
  unsigned u = __float_as_uint(f);
  return (u & 0x80000000u) ? ~u : (u | 0x80000000u);
}
__device__ __forceinline__ float mono2f(unsigned m) {
  unsigned u = (m & 0x80000000u) ? (m & 0x7FFFFFFFu) : ~m;
  return __uint_as_float(u);
}
constexpr unsigned MONO_NEG_INF = 0x007FFFFFu;

// ---- bf16 helpers ----
__device__ __forceinline__ unsigned short f2bf(float f) {
  unsigned u = __float_as_uint(f);
  unsigned r = (u + 0x7FFFu + ((u >> 16) & 1u)) >> 16;  // RNE
  return (unsigned short)r;
}
__device__ __forceinline__ float bf2f(unsigned short h) {
  return __uint_as_float((unsigned)h << 16);
}
__device__ __forceinline__ float bflo(unsigned u) { return __uint_as_float(u << 16); }
__device__ __forceinline__ float bfhi(unsigned u) { return __uint_as_float(u & 0xFFFF0000u); }

// ======= fused prep: hist | build_wT | init_mono | watt =======
constexpr int HIST_BLOCKS = (N_EDGES + 255) / 256;               // 3125
constexpr int WT_BLOCKS = (MBIG * F_IN + 255) / 256;             // 160

__global__ __launch_bounds__(256) void pre_fused(
    const float* __restrict__ W_root, const float* __restrict__ W_rel,
    const float* __restrict__ W_gat,
    const float* __restrict__ att_src, const float* __restrict__ att_dst,
    const int* __restrict__ dst,
    unsigned short* __restrict__ WbT_hi, unsigned short* __restrict__ WbT_lo,
    int* __restrict__ deg, int* __restrict__ rank,
    unsigned* __restrict__ pm,
    float* __restrict__ was, float* __restrict__ wad) {
  int b = blockIdx.x;
  if (b < HIST_BLOCKS) {
    int e = b * 256 + threadIdx.x;
    if (e < N_EDGES) rank[e] = atomicAdd(&deg[dst[e]], 1);
  } else if (b < HIST_BLOCKS + WT_BLOCKS) {
    int i = (b - HIST_BLOCKS) * 256 + threadIdx.x;
    if (i < MBIG * F_IN) {
      int c = i / F_IN, k = i % F_IN;
      float w = (c < H1) ? W_root[k * H1 + c]
                         : W_rel[((size_t)(((c - H1) >> 6) * F_IN + k)) * H1 + ((c - H1) & 63)];
      unsigned short hi = f2bf(w);
      WbT_hi[i] = hi;
      WbT_lo[i] = f2bf(w - bf2f(hi));
    }
  } else if (b == HIST_BLOCKS + WT_BLOCKS) {
    for (int i = threadIdx.x; i < N_GRAPHS * 16; i += 256) pm[i] = MONO_NEG_INF;
  } else {
    // watt: was/wad[k*4+hh] = sum_d W_gat[k][hh*32+d] * att[hh][d]
    int t = threadIdx.x;          // t = k*4 + hh, 256 threads exactly
    int k = t >> 2, hh = t & 3;
    float s = 0.f, d2 = 0.f;
#pragma unroll 8
    for (int dd = 0; dd < D_H; ++dd) {
      float wg = W_gat[k * HOUT + hh * D_H + dd];
      s += wg * att_src[hh * D_H + dd];
      d2 += wg * att_dst[hh * D_H + dd];
    }
    was[t] = s;
    wad[t] = d2;
  }
}

// ============ gemm1 body: K=128, f32 A, async double-buffered chunks ======
__device__ __forceinline__ void gemm_body128(int bx, int by,
    const float* __restrict__ Af,
    const unsigned short* __restrict__ BT_hi,
    const unsigned short* __restrict__ BT_lo,
    unsigned short* __restrict__ Cbf, int N, int M) {
  constexpr int K = 128, KC = 64;
  __shared__ unsigned short Ah[64 * KC];
  __shared__ unsigned short Al[64 * KC];
  const int tid = threadIdx.x;
  const int rowBase = bx * 64;
  const int colBase = by * 64;
  const int wv = tid >> 6, lane = tid & 63;
  const int wr = (wv >> 1) * 32, wc = (wv & 1) * 32;
  const int lrow = lane & 15, lkc = lane >> 4;
  int r_[4], c4_[4];
#pragma unroll
  for (int it = 0; it < 4; ++it) {
    int s = it * 256 + tid;
    r_[it] = s >> 4;
    c4_[it] = (s & 15) * 4;
  }
  f32x4 acc[2][2] = {};
#pragma unroll
  for (int it = 0; it < 4; ++it) {
    int gr = rowBase + r_[it];
    float4 v = make_float4(0.f, 0.f, 0.f, 0.f);
    if (gr < N) v = *reinterpret_cast<const float4*>(&Af[(size_t)gr * K + c4_[it]]);
    ushort4 hi, lo;
    hi.x = f2bf(v.x); lo.x = f2bf(v.x - bf2f(hi.x));
    hi.y = f2bf(v.y); lo.y = f2bf(v.y - bf2f(hi.y));
    hi.z = f2bf(v.z); lo.z = f2bf(v.z - bf2f(hi.z));
    hi.w = f2bf(v.w); lo.w = f2bf(v.w - bf2f(hi.w));
    int sw = c4_[it] ^ ((r_[it] & 7) << 3);
    *reinterpret_cast<ushort4*>(&Ah[r_[it] * KC + sw]) = hi;
    *reinterpret_cast<ushort4*>(&Al[r_[it] * KC + sw]) = lo;
  }
  __syncthreads();
  float4 v1[4];
#pragma unroll
  for (int it = 0; it < 4; ++it) {
    int gr = rowBase + r_[it];
    v1[it] = make_float4(0.f, 0.f, 0.f, 0.f);
    if (gr < N) v1[it] = *reinterpret_cast<const float4*>(&Af[(size_t)gr * K + KC + c4_[it]]);
  }
#pragma unroll
  for (int ch = 0; ch < 2; ++ch) {
    if (ch == 1) {
      __syncthreads();
#pragma unroll
      for (int it = 0; it < 4; ++it) {
        float4 v = v1[it];
        ushort4 hi, lo;
        hi.x = f2bf(v.x); lo.x = f2bf(v.x - bf2f(hi.x));
        hi.y = f2bf(v.y); lo.y = f2bf(v.y - bf2f(hi.y));
        hi.z = f2bf(v.z); lo.z = f2bf(v.z - bf2f(hi.z));
        hi.w = f2bf(v.w); lo.w = f2bf(v.w - bf2f(hi.w));
        int sw = c4_[it] ^ ((r_[it] & 7) << 3);
        *reinterpret_cast<ushort4*>(&Ah[r_[it] * KC + sw]) = hi;
        *reinterpret_cast<ushort4*>(&Al[r_[it] * KC + sw]) = lo;
      }
      __syncthreads();
    }
#pragma unroll
    for (int ks = 0; ks < KC; ks += 32) {
      bf16x8 ah[2], al[2], bh[2], bl[2];
#pragma unroll
      for (int fr = 0; fr < 2; ++fr) {
        int r = wr + fr * 16 + lrow;
        int sw = (ks + lkc * 8) ^ ((r & 7) << 3);
        ah[fr] = *reinterpret_cast<const bf16x8*>(&Ah[r * KC + sw]);
        al[fr] = *reinterpret_cast<const bf16x8*>(&Al[r * KC + sw]);
      }
#pragma unroll
      for (int fc = 0; fc < 2; ++fc) {
        int c = colBase + wc + fc * 16 + lrow;
        bh[fc] = *reinterpret_cast<const bf16x8*>(&BT_hi[(size_t)c * K + ch * KC + ks + lkc * 8]);
        bl[fc] = *reinterpret_cast<const bf16x8*>(&BT_lo[(size_t)c * K + ch * KC + ks + lkc * 8]);
      }
#pragma unroll
      for (int fr = 0; fr < 2; ++fr)
#pragma unroll
        for (int fc = 0; fc < 2; ++fc) {
          acc[fr][fc] = __builtin_amdgcn_mfma_f32_16x16x32_bf16(ah[fr], bh[fc], acc[fr][fc], 0, 0, 0);
          acc[fr][fc] = __builtin_amdgcn_mfma_f32_16x16x32_bf16(ah[fr], bl[fc], acc[fr][fc], 0, 0, 0);
          acc[fr][fc] = __builtin_amdgcn_mfma_f32_16x16x32_bf16(al[fr], bh[fc], acc[fr][fc], 0, 0, 0);
        }
    }
  }
#pragma unroll
  for (int fr = 0; fr < 2; ++fr) {
#pragma unroll
    for (int i = 0; i < 4; ++i) {
      int row = rowBase + wr + fr * 16 + lkc * 4 + i;
      if (row < N) {
#pragma unroll
        for (int fc = 0; fc < 2; ++fc) {
          int col = colBase + wc + fc * 16 + lrow;
          Cbf[(size_t)row * M + col] = f2bf(acc[fr][fc][i]);
        }
      }
    }
  }
}

// ---- gemm1 (xt from f32 x) fused with CSR fill; XCD-group swizzle ----
constexpr int G1_BX = N_PAD / 64;          // 782
constexpr int G1_GRID = 3920;              // 8 * 5 * 98
__global__ __launch_bounds__(256) void gemm1_fill(
    const float* __restrict__ x,
    const unsigned short* __restrict__ wbt_hi, const unsigned short* __restrict__ wbt_lo,
    unsigned short* __restrict__ xtbf,
    const int* __restrict__ src, const int* __restrict__ dst,
    const int* __restrict__ etype, const int* __restrict__ off,
    const int* __restrict__ rank, int* __restrict__ eprep) {
  if (blockIdx.x < G1_GRID) {
    int b = blockIdx.x;
    int r8 = b & 7, s = b >> 3;
    int by = s % 5, q = s / 5;
    int bx = q * 8 + r8;
    if (bx < G1_BX)
      gemm_body128(bx, by, x, wbt_hi, wbt_lo, xtbf, N_NODES, MBIG);
  } else {
    int e = (blockIdx.x - G1_GRID) * 256 + threadIdx.x;
    if (e < N_EDGES) {
      int pos = off[dst[e]] + rank[e];
      eprep[pos] = src[e] | (etype[e] << 16);
    }
  }
}

// ---- scan stage 1: per-block sums ----
__global__ __launch_bounds__(256) void k_s1(const int* __restrict__ deg,
                                            int* __restrict__ bsum) {
  __shared__ int ss[256];
  int t = threadIdx.x;
  int i = blockIdx.x * 256 + t;
  ss[t] = (i < N_NODES) ? deg[i] : 0;
  __syncthreads();
  for (int d = 128; d > 0; d >>= 1) {
    if (t < d) ss[t] += ss[t + d];
    __syncthreads();
  }
  if (t == 0) bsum[blockIdx.x] = ss[0];
}

// ---- scan stage 2: exclusive scan of block sums ----
__global__ __launch_bounds__(256) void k_s2(const int* __restrict__ bsum,
                                            int* __restrict__ bbase,
                                            int* __restrict__ off) {
  __shared__ int ss[256];
  int t = threadIdx.x;
  int v = (t < NBLK) ? bsum[t] : 0;
  ss[t] = v;
  __syncthreads();
  for (int d = 1; d < 256; d <<= 1) {
    int u = (t >= d) ? ss[t - d] : 0;
    __syncthreads();
    ss[t] += u;
    __syncthreads();
  }
  if (t < NBLK) bbase[t] = ss[t] - v;
  if (t == NBLK - 1) off[N_NODES] = ss[t];
}

// ---- scan stage 3: block-local scan + base ----
__global__ __launch_bounds__(256) void k_s3(const int* __restrict__ deg,
                                            const int* __restrict__ bbase,
                                            int* __restrict__ off) {
  __shared__ int ss[256];
  int t = threadIdx.x;
  int i = blockIdx.x * 256 + t;
  int v = (i < N_NODES) ? deg[i] : 0;
  ss[t] = v;
  __syncthreads();
  for (int d = 1; d < 256; d <<= 1) {
    int u = (t >= d) ? ss[t - d] : 0;
    __syncthreads();
    ss[t] += u;
    __syncthreads();
  }
  if (i < N_NODES) off[i] = bbase[blockIdx.x] + ss[t] - v;
}

// ---- RGCN: gather from bf16 xt; wave/node; computes h in-register, then
//      FUSED: a_s/a_d = h @ (W_gat @ att)  AND  g = h @ W_gat (bf16 out),
//      reading W_gat in its NATURAL [k][c] layout (coalesced float2). ----
__global__ __launch_bounds__(256) void rgcn_gather(const unsigned short* __restrict__ xtbf,
                                                   const int* __restrict__ off,
                                                   const int* __restrict__ eprep,
                                                   const float* __restrict__ b_rgcn,
                                                   const float* __restrict__ was,
                                                   const float* __restrict__ wad,
                                                   const float* __restrict__ W_gat,
                                                   unsigned short* __restrict__ gbf,
                                                   float* __restrict__ a_s,
                                                   float* __restrict__ a_d) {
  __shared__ float h_lds[4][H1];
  int wid = (blockIdx.x * 256 + threadIdx.x) >> 6;
  int wv = threadIdx.x >> 6;
  int lane = threadIdx.x & 63;
  int half = lane >> 5;
  int cp = lane & 31;
  int start = off[wid], end = off[wid + 1];
  float a0x=0.f,a0y=0.f,a1x=0.f,a1y=0.f,a2x=0.f,a2y=0.f,a3x=0.f,a3y=0.f;
  int c0=0,c1=0,c2=0,c3=0;
  int niter = (end - start + 1) >> 1;
  for (int t = 0; t < niter; t += 2) {
    int idx0 = start + 2 * t + half;
    int idx1 = idx0 + 2;
    int p0 = (idx0 < end) ? eprep[idx0] : 0x70000;
    int p1 = (idx1 < end) ? eprep[idx1] : 0x70000;
    int s0 = p0 & 0xFFFF, r0 = p0 >> 16;
    int s1 = p1 & 0xFFFF, r1 = p1 >> 16;
    unsigned u0 = *reinterpret_cast<const unsigned*>(
        &xtbf[(size_t)s0 * MBIG + H1 + (r0 << 6) + cp * 2]);
    unsigned u1 = *reinterpret_cast<const unsigned*>(
        &xtbf[(size_t)s1 * MBIG + H1 + (r1 << 6) + cp * 2]);
    float v0x = bflo(u0), v0y = bfhi(u0);
    float v1x = bflo(u1), v1y = bfhi(u1);
    a0x += (r0==0)?v0x:0.f; a0y += (r0==0)?v0y:0.f; c0 += (r0==0);
    a1x += (r0==1)?v0x:0.f; a1y += (r0==1)?v0y:0.f; c1 += (r0==1);
    a2x += (r0==2)?v0x:0.f; a2y += (r0==2)?v0y:0.f; c2 += (r0==2);
    a3x += (r0==3)?v0x:0.f; a3y += (r0==3)?v0y:0.f; c3 += (r0==3);
    a0x += (r1==0)?v1x:0.f; a0y += (r1==0)?v1y:0.f; c0 += (r1==0);
    a1x += (r1==1)?v1x:0.f; a1y += (r1==1)?v1y:0.f; c1 += (r1==1);
    a2x += (r1==2)?v1x:0.f; a2y += (r1==2)?v1y:0.f; c2 += (r1==2);
    a3x += (r1==3)?v1x:0.f; a3y += (r1==3)?v1y:0.f; c3 += (r1==3);
  }
  a0x += __shfl_xor(a0x, 32); a0y += __shfl_xor(a0y, 32);
  a1x += __shfl_xor(a1x, 32); a1y += __shfl_xor(a1y, 32);
  a2x += __shfl_xor(a2x, 32); a2y += __shfl_xor(a2y, 32);
  a3x += __shfl_xor(a3x, 32); a3y += __shfl_xor(a3y, 32);
  c0 += __shfl_xor(c0, 32); c1 += __shfl_xor(c1, 32);
  c2 += __shfl_xor(c2, 32); c3 += __shfl_xor(c3, 32);
  if (half == 0) {
    unsigned ur = *reinterpret_cast<const unsigned*>(&xtbf[(size_t)wid * MBIG + cp * 2]);
    float2 bb = *reinterpret_cast<const float2*>(&b_rgcn[cp * 2]);
    float i0 = 1.0f / (float)max(c0, 1);
    float i1 = 1.0f / (float)max(c1, 1);
    float i2 = 1.0f / (float)max(c2, 1);
    float i3 = 1.0f / (float)max(c3, 1);
    float vx = bflo(ur) + bb.x + a0x * i0 + a1x * i1 + a2x * i2 + a3x * i3;
    float vy = bfhi(ur) + bb.y + a0y * i0 + a1y * i1 + a2y * i2 + a3y * i3;
    vx = fmaxf(vx, 0.f);
    vy = fmaxf(vy, 0.f);
    h_lds[wv][cp * 2] = vx;
    h_lds[wv][cp * 2 + 1] = vy;
    // ---- attention coefficients: a = h @ was / h @ wad ----
    float4 wsA = *reinterpret_cast<const float4*>(&was[cp * 8]);      // k=2cp
    float4 wsB = *reinterpret_cast<const float4*>(&was[cp * 8 + 4]);  // k=2cp+1
    float4 wdA = *reinterpret_cast<const float4*>(&wad[cp * 8]);
    float4 wdB = *reinterpret_cast<const float4*>(&wad[cp * 8 + 4]);
    float ps0 = vx * wsA.x + vy * wsB.x;
    float ps1 = vx * wsA.y + vy * wsB.y;
    float ps2 = vx * wsA.z + vy * wsB.z;
    float ps3 = vx * wsA.w + vy * wsB.w;
    float pd0 = vx * wdA.x + vy * wdB.x;
    float pd1 = vx * wdA.y + vy * wdB.y;
    float pd2 = vx * wdA.z + vy * wdB.z;
    float pd3 = vx * wdA.w + vy * wdB.w;
#pragma unroll
    for (int d = 1; d < 32; d <<= 1) {
      ps0 += __shfl_xor(ps0, d); ps1 += __shfl_xor(ps1, d);
      ps2 += __shfl_xor(ps2, d); ps3 += __shfl_xor(ps3, d);
      pd0 += __shfl_xor(pd0, d); pd1 += __shfl_xor(pd1, d);
      pd2 += __shfl_xor(pd2, d); pd3 += __shfl_xor(pd3, d);
    }
    if (cp == 0) {
      *reinterpret_cast<float4*>(&a_s[(size_t)wid * 4]) = make_float4(ps0, ps1, ps2, ps3);
      *reinterpret_cast<float4*>(&a_d[(size_t)wid * 4]) = make_float4(pd0, pd1, pd2, pd3);
    }
  }
  __syncthreads();
  // ---- fused gemm2 (coalesced): g[c] = sum_k h[k] * W_gat[k][c],
  //      c = 2*lane, 2*lane+1; W_gat natural layout, float2/row (512 B/wave)
  float g0 = 0.f, g1 = 0.f;
#pragma unroll 16
  for (int k = 0; k < H1; ++k) {
    float hk = h_lds[wv][k];                      // LDS broadcast
    float2 w = *reinterpret_cast<const float2*>(&W_gat[(size_t)k * HOUT + 2 * lane]);
    g0 += hk * w.x;
    g1 += hk * w.y;
  }
  unsigned gp = (unsigned)f2bf(g0) | ((unsigned)f2bf(g1) << 16);
  *reinterpret_cast<unsigned*>(&gbf[(size_t)wid * HOUT + lane * 2]) = gp;
}

// ---- GAT + head fused ----
constexpr int GAT_BLOCKS = 2048;
constexpr int GAT_WAVES = GAT_BLOCKS * 4;   // 8192
__global__ __launch_bounds__(256) void gat_fused(const unsigned short* __restrict__ gbf,
                                                 const float* __restrict__ a_s,
                                                 const float* __restrict__ a_d,
                                                 const int* __restrict__ off,
                                                 const int* __restrict__ eprep,
                                                 const float* __restrict__ b_gat,
                                                 const float* __restrict__ W1,
                                                 const float* __restrict__ b1,
                                                 const int* __restrict__ batch,
                                                 unsigned* __restrict__ p_mono) {
  __shared__ float w1s[HOUT * 16];        // W1[k][j]
  __shared__ float ob[4][HOUT];           // per-wave o row
  __shared__ unsigned sp[N_GRAPHS * 16];
  const int t = threadIdx.x;
  for (int i = t; i < HOUT * 16; i += 256) w1s[i] = W1[i];
  for (int i = t; i < N_GRAPHS * 16; i += 256) sp[i] = MONO_NEG_INF;
  __syncthreads();
  const int wv = t >> 6, lane = t & 63;
  const int hh = lane >> 4;
  const int jj = lane & 15, grp = lane >> 4;
  const int w = blockIdx.x * 4 + wv;
  const int q = N_NODES / GAT_WAVES;
  const int r = N_NODES % GAT_WAVES;
  const int nbeg = w * q + ((w < r) ? w : r);
  const int ncnt = q + ((w < r) ? 1 : 0);
  for (int wid = nbeg; wid < nbeg + ncnt; ++wid) {
    int start = off[wid], end = off[wid + 1];
    float4 ad4 = *reinterpret_cast<const float4*>(a_d + (size_t)wid * 4);
    float adh = (hh == 0) ? ad4.x : (hh == 1) ? ad4.y : (hh == 2) ? ad4.z : ad4.w;
    float ox = 0.f, oy = 0.f, den = 0.f;
    int i = start;
    for (; i + 4 <= end; i += 4) {
      int p0 = eprep[i], p1 = eprep[i + 1], p2 = eprep[i + 2], p3 = eprep[i + 3];
      int s0 = p0 & 0xFFFF, s1 = p1 & 0xFFFF, s2 = p2 & 0xFFFF, s3 = p3 & 0xFFFF;
      float as0 = a_s[(size_t)s0 * 4 + hh];
      float as1 = a_s[(size_t)s1 * 4 + hh];
      float as2 = a_s[(size_t)s2 * 4 + hh];
      float as3 = a_s[(size_t)s3 * 4 + hh];
      unsigned u0 = *reinterpret_cast<const unsigned*>(&gbf[(size_t)s0 * HOUT + lane * 2]);
      unsigned u1 = *reinterpret_cast<const unsigned*>(&gbf[(size_t)s1 * HOUT + lane * 2]);
      unsigned u2 = *reinterpret_cast<const unsigned*>(&gbf[(size_t)s2 * HOUT + lane * 2]);
      unsigned u3 = *reinterpret_cast<const unsigned*>(&gbf[(size_t)s3 * HOUT + lane * 2]);
      float e0 = as0 + adh; e0 = (e0 > 0.f) ? e0 : 0.2f * e0;
      float e1 = as1 + adh; e1 = (e1 > 0.f) ? e1 : 0.2f * e1;
      float e2 = as2 + adh; e2 = (e2 > 0.f) ? e2 : 0.2f * e2;
      float e3 = as3 + adh; e3 = (e3 > 0.f) ? e3 : 0.2f * e3;
      float x0 = __expf(e0), x1 = __expf(e1), x2 = __expf(e2), x3 = __expf(e3);
      den += x0 + x1 + x2 + x3;
      ox += x0 * bflo(u0) + x1 * bflo(u1) + x2 * bflo(u2) + x3 * bflo(u3);
      oy += x0 * bfhi(u0) + x1 * bfhi(u1) + x2 * bfhi(u2) + x3 * bfhi(u3);
    }
    for (; i < end; ++i) {
      int p = eprep[i];
      int s = p & 0xFFFF;
      float as = a_s[(size_t)s * 4 + hh];
      unsigned u = *reinterpret_cast<const unsigned*>(&gbf[(size_t)s * HOUT + lane * 2]);
      float e = as + adh; e = (e > 0.f) ? e : 0.2f * e;
      float ex = __expf(e);
      den += ex;
      ox += ex * bflo(u);
      oy += ex * bfhi(u);
    }
    float dinv = (den > 0.f) ? (1.0f / den) : 0.f;
    float2 bg = *reinterpret_cast<const float2*>(b_gat + lane * 2);
    float vx = ox * dinv + bg.x; vx = (vx > 0.f) ? vx : 0.01f * vx;
    float vy = oy * dinv + bg.y; vy = (vy > 0.f) ? vy : 0.01f * vy;
    *reinterpret_cast<float2*>(&ob[wv][lane * 2]) = make_float2(vx, vy);
    float acc = 0.f;
#pragma unroll 8
    for (int i2 = 0; i2 < 32; ++i2) {
      int c = grp + 4 * i2;
      acc += ob[wv][c] * w1s[c * 16 + jj];
    }
    acc += __shfl_xor(acc, 16);
    acc += __shfl_xor(acc, 32);
    float z = acc + b1[jj];
    z = (z > 0.f) ? z : 0.01f * z;
    int b = batch[wid];
    if (lane < 16) atomicMax(&sp[b * 16 + jj], f2mono(z));
  }
  __syncthreads();
  for (int i = t; i < N_GRAPHS * 16; i += 256) {
    unsigned v = sp[i];
    if (v != MONO_NEG_INF) atomicMax(p_mono + i, v);
  }
}

// ---- y = p @ W2 + b2 ----
__global__ void final_y(const unsigned* __restrict__ p_mono,
                        const float* __restrict__ W2,
                        const float* __restrict__ b2,
                        float* __restrict__ y) {
  int gr = threadIdx.x;
  if (gr >= N_GRAPHS) return;
  float acc = b2[0];
#pragma unroll
  for (int k = 0; k < 16; ++k) acc += mono2f(p_mono[gr * 16 + k]) * W2[k];
  y[gr] = acc;
}

extern "C" void kernel_launch(void* const* d_in, const int* in_sizes, int n_in,
                              void* d_out, int out_size, void* d_ws, size_t ws_size,
                              hipStream_t stream) {
  const float* x       = (const float*)d_in[0];
  const int*   eidx    = (const int*)d_in[1];
  const int*   etype   = (const int*)d_in[2];
  const int*   batch   = (const int*)d_in[3];
  const float* W_rel   = (const float*)d_in[4];
  const float* W_root  = (const float*)d_in[5];
  const float* b_rgcn  = (const float*)d_in[6];
  const float* W_gat   = (const float*)d_in[7];
  const float* att_src = (const float*)d_in[8];
  const float* att_dst = (const float*)d_in[9];
  const float* b_gat   = (const float*)d_in[10];
  const float* W1      = (const float*)d_in[11];
  const float* b1      = (const float*)d_in[12];
  const float* W2      = (const float*)d_in[13];
  const float* b2      = (const float*)d_in[14];
  float* y = (float*)d_out;

  const int* src = eidx;
  const int* dst = eidx + N_EDGES;

  float* ws = (float*)d_ws;
  // ---- workspace layout (float offsets) ----
  const size_t OFF_XTBF= 0;           //  8,007,680 f: xt bf16 [N_PAD,320]
  const size_t OFF_GBF = 8007680;     //  3,203,072 f: g bf16 [N_PAD,128]
  const size_t OFF_AS  = 11210752;    //    200,000  a_src
  const size_t OFF_AD  = 11410752;    //    200,000  a_dst
  const size_t OFF_PM  = 11610752;    //      1,024 f = 1024 u32 pool max
  const size_t OFF_DEG = 11611776;    //     50,000  deg (int)
  const size_t OFF_OFFS= 11661776;    //     50,001  off (int)
  const size_t OFF_RANK= 11711780;    //    800,000  rank (int)
  const size_t OFF_EP  = 12511780;    //    800,000  eprep (int)
  const size_t OFF_BS  = 13311780;    //        196
  const size_t OFF_BB  = 13311976;    //        196
  const size_t OFF_WAS = 13312176;    //        256  was (16B aligned)
  const size_t OFF_WAD = 13312432;    //        256  wad
  const size_t OFF_WBH = 13312688;    //     20,480  WbigT_hi (16B aligned)
  const size_t OFF_WBL = 13333168;    //     20,480  WbigT_lo
  const size_t TOTAL_F = 13353648;
  if (ws_size < TOTAL_F * sizeof(float)) return;

  unsigned short* xtbf = (unsigned short*)(ws + OFF_XTBF);
  unsigned short* gbf  = (unsigned short*)(ws + OFF_GBF);
  float* a_s   = ws + OFF_AS;
  float* a_d   = ws + OFF_AD;
  unsigned* pm = (unsigned*)(ws + OFF_PM);
  int* deg     = (int*)(ws + OFF_DEG);
  int* offs    = (int*)(ws + OFF_OFFS);
  int* rank    = (int*)(ws + OFF_RANK);
  int* eprep   = (int*)(ws + OFF_EP);
  int* bsum    = (int*)(ws + OFF_BS);
  int* bbase   = (int*)(ws + OFF_BB);
  float* was   = ws + OFF_WAS;
  float* wad   = ws + OFF_WAD;
  unsigned short* wbt_hi = (unsigned short*)(ws + OFF_WBH);
  unsigned short* wbt_lo = (unsigned short*)(ws + OFF_WBL);

  // 1. deg = 0 (before fused hist)
  hipMemsetAsync(deg, 0, N_NODES * sizeof(int), stream);

  // 2. fused prep: hist(+rank) | build_wT | init_mono | watt
  pre_fused<<<HIST_BLOCKS + WT_BLOCKS + 2, 256, 0, stream>>>(
      W_root, W_rel, W_gat, att_src, att_dst, dst,
      wbt_hi, wbt_lo, deg, rank, pm, was, wad);

  // 3. scan (off from deg)
  k_s1<<<NBLK, 256, 0, stream>>>(deg, bsum);
  k_s2<<<1, 256, 0, stream>>>(bsum, bbase, offs);
  k_s3<<<NBLK, 256, 0, stream>>>(deg, bbase, offs);

  // 4. gemm1 (XCD-swizzled, async dbuf chunks) fused with CSR fill
  gemm1_fill<<<G1_GRID + HIST_BLOCKS, 256, 0, stream>>>(
      x, wbt_hi, wbt_lo, xtbf, src, dst, etype, offs, rank, eprep);

  // 5. RGCN gather -> h (regs) + fused a_s/a_d + fused g (coalesced W_gat)
  rgcn_gather<<<N_NODES / 4, 256, 0, stream>>>(xtbf, offs, eprep, b_rgcn,
                                               was, wad, W_gat,
                                               gbf, a_s, a_d);

  // 6. fused GAT aggregation + head + per-graph max pool
  gat_fused<<<GAT_BLOCKS, 256, 0, stream>>>(gbf, a_s, a_d, offs, eprep, b_gat,
                                            W1, b1, batch, pm);

  // 7. y = p @ W2 + b2
  final_y<<<1, 64, 0, stream>>>(pm, W2, b2, y);
}

// Round 20
// 207.721 us; speedup vs baseline: 1.8356x; 1.2792x over previous
//
#include <hip/hip_runtime.h>
#include <hip/hip_bf16.h>

constexpr int N_NODES = 50000;
constexpr int N_EDGES = 800000;
constexpr int F_IN = 128;
constexpr int H1 = 64;
constexpr int HEADS = 4;
constexpr int D_H = 32;
constexpr int HOUT = HEADS * D_H;       // 128
constexpr int N_REL = 4;
constexpr int N_GRAPHS = 64;
constexpr int MBIG = H1 * (1 + N_REL);  // 320
constexpr int NBLK = (N_NODES + 255) / 256;  // 196
constexpr int N_PAD = 50048;            // 64 * 782

typedef __attribute__((ext_vector_type(8))) short bf16x8;
typedef __attribute__((ext_vector_type(4))) float f32x4;

// ---- monotonic float<->uint for atomicMax on floats ----
__device__ __forceinline__ unsigned f2mono(float f) {
  unsigned u = __float_as_uint(f);
  return (u & 0x80000000u) ? ~u : (u | 0x80000000u);
}
__device__ __forceinline__ float mono2f(unsigned m) {
  unsigned u = (m & 0x80000000u) ? (m & 0x7FFFFFFFu) : ~m;
  return __uint_as_float(u);
}
constexpr unsigned MONO_NEG_INF = 0x007FFFFFu;

// ---- bf16 helpers ----
__device__ __forceinline__ unsigned short f2bf(float f) {
  unsigned u = __float_as_uint(f);
  unsigned r = (u + 0x7FFFu + ((u >> 16) & 1u)) >> 16;  // RNE
  return (unsigned short)r;
}
__device__ __forceinline__ float bf2f(unsigned short h) {
  return __uint_as_float((unsigned)h << 16);
}
__device__ __forceinline__ float bflo(unsigned u) { return __uint_as_float(u << 16); }
__device__ __forceinline__ float bfhi(unsigned u) { return __uint_as_float(u & 0xFFFF0000u); }

// ======= fused prep: hist | build_wT | init_mono | watt =======
constexpr int HIST_BLOCKS = (N_EDGES + 255) / 256;               // 3125
constexpr int WT_BLOCKS = (MBIG * F_IN + HOUT * H1 + 255) / 256; // 192

__global__ __launch_bounds__(256) void pre_fused(
    const float* __restrict__ W_root, const float* __restrict__ W_rel,
    const float* __restrict__ W_gat,
    const float* __restrict__ att_src, const float* __restrict__ att_dst,
    const int* __restrict__ dst,
    unsigned short* __restrict__ WbT_hi, unsigned short* __restrict__ WbT_lo,
    unsigned short* __restrict__ WgT_hi, unsigned short* __restrict__ WgT_lo,
    int* __restrict__ deg, int* __restrict__ rank,
    unsigned* __restrict__ pm,
    float* __restrict__ was, float* __restrict__ wad) {
  int b = blockIdx.x;
  if (b < HIST_BLOCKS) {
    int e = b * 256 + threadIdx.x;
    if (e < N_EDGES) rank[e] = atomicAdd(&deg[dst[e]], 1);
  } else if (b < HIST_BLOCKS + WT_BLOCKS) {
    int i = (b - HIST_BLOCKS) * 256 + threadIdx.x;
    if (i < MBIG * F_IN) {
      int c = i / F_IN, k = i % F_IN;
      float w = (c < H1) ? W_root[k * H1 + c]
                         : W_rel[((size_t)(((c - H1) >> 6) * F_IN + k)) * H1 + ((c - H1) & 63)];
      unsigned short hi = f2bf(w);
      WbT_hi[i] = hi;
      WbT_lo[i] = f2bf(w - bf2f(hi));
    } else {
      int j = i - MBIG * F_IN;
      if (j < HOUT * H1) {
        int c = j / H1, k = j % H1;
        float w = W_gat[k * HOUT + c];
        unsigned short hi = f2bf(w);
        WgT_hi[j] = hi;
        WgT_lo[j] = f2bf(w - bf2f(hi));
      }
    }
  } else if (b == HIST_BLOCKS + WT_BLOCKS) {
    for (int i = threadIdx.x; i < N_GRAPHS * 16; i += 256) pm[i] = MONO_NEG_INF;
  } else {
    // watt: was/wad[k*4+hh] = sum_d W_gat[k][hh*32+d] * att[hh][d]
    int t = threadIdx.x;          // t = k*4 + hh, 256 threads exactly
    int k = t >> 2, hh = t & 3;
    float s = 0.f, d2 = 0.f;
#pragma unroll 8
    for (int dd = 0; dd < D_H; ++dd) {
      float wg = W_gat[k * HOUT + hh * D_H + dd];
      s += wg * att_src[hh * D_H + dd];
      d2 += wg * att_dst[hh * D_H + dd];
    }
    was[t] = s;
    wad[t] = d2;
  }
}

// ============ gemm1 body: K=128, f32 A, async double-buffered chunks ======
__device__ __forceinline__ void gemm_body128(int bx, int by,
    const float* __restrict__ Af,
    const unsigned short* __restrict__ BT_hi,
    const unsigned short* __restrict__ BT_lo,
    unsigned short* __restrict__ Cbf, int N, int M) {
  constexpr int K = 128, KC = 64;
  __shared__ unsigned short Ah[64 * KC];
  __shared__ unsigned short Al[64 * KC];
  const int tid = threadIdx.x;
  const int rowBase = bx * 64;
  const int colBase = by * 64;
  const int wv = tid >> 6, lane = tid & 63;
  const int wr = (wv >> 1) * 32, wc = (wv & 1) * 32;
  const int lrow = lane & 15, lkc = lane >> 4;
  int r_[4], c4_[4];
#pragma unroll
  for (int it = 0; it < 4; ++it) {
    int s = it * 256 + tid;
    r_[it] = s >> 4;
    c4_[it] = (s & 15) * 4;
  }
  f32x4 acc[2][2] = {};
#pragma unroll
  for (int it = 0; it < 4; ++it) {
    int gr = rowBase + r_[it];
    float4 v = make_float4(0.f, 0.f, 0.f, 0.f);
    if (gr < N) v = *reinterpret_cast<const float4*>(&Af[(size_t)gr * K + c4_[it]]);
    ushort4 hi, lo;
    hi.x = f2bf(v.x); lo.x = f2bf(v.x - bf2f(hi.x));
    hi.y = f2bf(v.y); lo.y = f2bf(v.y - bf2f(hi.y));
    hi.z = f2bf(v.z); lo.z = f2bf(v.z - bf2f(hi.z));
    hi.w = f2bf(v.w); lo.w = f2bf(v.w - bf2f(hi.w));
    int sw = c4_[it] ^ ((r_[it] & 7) << 3);
    *reinterpret_cast<ushort4*>(&Ah[r_[it] * KC + sw]) = hi;
    *reinterpret_cast<ushort4*>(&Al[r_[it] * KC + sw]) = lo;
  }
  __syncthreads();
  float4 v1[4];
#pragma unroll
  for (int it = 0; it < 4; ++it) {
    int gr = rowBase + r_[it];
    v1[it] = make_float4(0.f, 0.f, 0.f, 0.f);
    if (gr < N) v1[it] = *reinterpret_cast<const float4*>(&Af[(size_t)gr * K + KC + c4_[it]]);
  }
#pragma unroll
  for (int ch = 0; ch < 2; ++ch) {
    if (ch == 1) {
      __syncthreads();
#pragma unroll
      for (int it = 0; it < 4; ++it) {
        float4 v = v1[it];
        ushort4 hi, lo;
        hi.x = f2bf(v.x); lo.x = f2bf(v.x - bf2f(hi.x));
        hi.y = f2bf(v.y); lo.y = f2bf(v.y - bf2f(hi.y));
        hi.z = f2bf(v.z); lo.z = f2bf(v.z - bf2f(hi.z));
        hi.w = f2bf(v.w); lo.w = f2bf(v.w - bf2f(hi.w));
        int sw = c4_[it] ^ ((r_[it] & 7) << 3);
        *reinterpret_cast<ushort4*>(&Ah[r_[it] * KC + sw]) = hi;
        *reinterpret_cast<ushort4*>(&Al[r_[it] * KC + sw]) = lo;
      }
      __syncthreads();
    }
#pragma unroll
    for (int ks = 0; ks < KC; ks += 32) {
      bf16x8 ah[2], al[2], bh[2], bl[2];
#pragma unroll
      for (int fr = 0; fr < 2; ++fr) {
        int r = wr + fr * 16 + lrow;
        int sw = (ks + lkc * 8) ^ ((r & 7) << 3);
        ah[fr] = *reinterpret_cast<const bf16x8*>(&Ah[r * KC + sw]);
        al[fr] = *reinterpret_cast<const bf16x8*>(&Al[r * KC + sw]);
      }
#pragma unroll
      for (int fc = 0; fc < 2; ++fc) {
        int c = colBase + wc + fc * 16 + lrow;
        bh[fc] = *reinterpret_cast<const bf16x8*>(&BT_hi[(size_t)c * K + ch * KC + ks + lkc * 8]);
        bl[fc] = *reinterpret_cast<const bf16x8*>(&BT_lo[(size_t)c * K + ch * KC + ks + lkc * 8]);
      }
#pragma unroll
      for (int fr = 0; fr < 2; ++fr)
#pragma unroll
        for (int fc = 0; fc < 2; ++fc) {
          acc[fr][fc] = __builtin_amdgcn_mfma_f32_16x16x32_bf16(ah[fr], bh[fc], acc[fr][fc], 0, 0, 0);
          acc[fr][fc] = __builtin_amdgcn_mfma_f32_16x16x32_bf16(ah[fr], bl[fc], acc[fr][fc], 0, 0, 0);
          acc[fr][fc] = __builtin_amdgcn_mfma_f32_16x16x32_bf16(al[fr], bh[fc], acc[fr][fc], 0, 0, 0);
        }
    }
  }
#pragma unroll
  for (int fr = 0; fr < 2; ++fr) {
#pragma unroll
    for (int i = 0; i < 4; ++i) {
      int row = rowBase + wr + fr * 16 + lkc * 4 + i;
      if (row < N) {
#pragma unroll
        for (int fc = 0; fc < 2; ++fc) {
          int col = colBase + wc + fc * 16 + lrow;
          Cbf[(size_t)row * M + col] = f2bf(acc[fr][fc][i]);
        }
      }
    }
  }
}

// ============ gemm2 body: K=64, pre-split hi/lo A, single chunk ==========
__device__ __forceinline__ void gemm_body64(int bx, int by,
    const unsigned short* __restrict__ Ahi_,
    const unsigned short* __restrict__ Alo_,
    const unsigned short* __restrict__ BT_hi,
    const unsigned short* __restrict__ BT_lo,
    unsigned short* __restrict__ Cbf, int N, int M) {
  constexpr int K = 64;
  __shared__ unsigned short Ah[64 * K];
  __shared__ unsigned short Al[64 * K];
  const int tid = threadIdx.x;
  const int rowBase = bx * 64;
  const int colBase = by * 64;
  constexpr int KQ8 = K / 8;
  for (int s = tid; s < 64 * KQ8; s += 256) {
    int r = s / KQ8, c8 = (s % KQ8) * 8;
    size_t gi = (size_t)(rowBase + r) * K + c8;
    int sw = c8 ^ ((r & 7) << 3);
    *reinterpret_cast<uint4*>(&Ah[r * K + sw]) =
        *reinterpret_cast<const uint4*>(&Ahi_[gi]);
    *reinterpret_cast<uint4*>(&Al[r * K + sw]) =
        *reinterpret_cast<const uint4*>(&Alo_[gi]);
  }
  __syncthreads();
  const int wv = tid >> 6, lane = tid & 63;
  const int wr = (wv >> 1) * 32, wc = (wv & 1) * 32;
  const int lrow = lane & 15, lkc = lane >> 4;
  f32x4 acc[2][2] = {};
#pragma unroll
  for (int ks = 0; ks < K; ks += 32) {
    bf16x8 ah[2], al[2], bh[2], bl[2];
#pragma unroll
    for (int fr = 0; fr < 2; ++fr) {
      int r = wr + fr * 16 + lrow;
      int sw = (ks + lkc * 8) ^ ((r & 7) << 3);
      ah[fr] = *reinterpret_cast<const bf16x8*>(&Ah[r * K + sw]);
      al[fr] = *reinterpret_cast<const bf16x8*>(&Al[r * K + sw]);
    }
#pragma unroll
    for (int fc = 0; fc < 2; ++fc) {
      int c = colBase + wc + fc * 16 + lrow;
      bh[fc] = *reinterpret_cast<const bf16x8*>(&BT_hi[(size_t)c * K + ks + lkc * 8]);
      bl[fc] = *reinterpret_cast<const bf16x8*>(&BT_lo[(size_t)c * K + ks + lkc * 8]);
    }
#pragma unroll
    for (int fr = 0; fr < 2; ++fr)
#pragma unroll
      for (int fc = 0; fc < 2; ++fc) {
        acc[fr][fc] = __builtin_amdgcn_mfma_f32_16x16x32_bf16(ah[fr], bh[fc], acc[fr][fc], 0, 0, 0);
        acc[fr][fc] = __builtin_amdgcn_mfma_f32_16x16x32_bf16(ah[fr], bl[fc], acc[fr][fc], 0, 0, 0);
        acc[fr][fc] = __builtin_amdgcn_mfma_f32_16x16x32_bf16(al[fr], bh[fc], acc[fr][fc], 0, 0, 0);
      }
  }
#pragma unroll
  for (int fr = 0; fr < 2; ++fr) {
#pragma unroll
    for (int i = 0; i < 4; ++i) {
      int row = rowBase + wr + fr * 16 + lkc * 4 + i;
      if (row < N) {
#pragma unroll
        for (int fc = 0; fc < 2; ++fc) {
          int col = colBase + wc + fc * 16 + lrow;
          Cbf[(size_t)row * M + col] = f2bf(acc[fr][fc][i]);
        }
      }
    }
  }
}

// ---- gemm1 (xt from f32 x) fused with CSR fill; XCD-group swizzle ----
constexpr int G1_BX = N_PAD / 64;          // 782
constexpr int G1_GRID = 3920;              // 8 * 5 * 98
__global__ __launch_bounds__(256) void gemm1_fill(
    const float* __restrict__ x,
    const unsigned short* __restrict__ wbt_hi, const unsigned short* __restrict__ wbt_lo,
    unsigned short* __restrict__ xtbf,
    const int* __restrict__ src, const int* __restrict__ dst,
    const int* __restrict__ etype, const int* __restrict__ off,
    const int* __restrict__ rank, int* __restrict__ eprep) {
  if (blockIdx.x < G1_GRID) {
    int b = blockIdx.x;
    int r8 = b & 7, s = b >> 3;
    int by = s % 5, q = s / 5;
    int bx = q * 8 + r8;
    if (bx < G1_BX)
      gemm_body128(bx, by, x, wbt_hi, wbt_lo, xtbf, N_NODES, MBIG);
  } else {
    int e = (blockIdx.x - G1_GRID) * 256 + threadIdx.x;
    if (e < N_EDGES) {
      int pos = off[dst[e]] + rank[e];
      eprep[pos] = src[e] | (etype[e] << 16);
    }
  }
}

// ---- gemm2 (K=64, g from pre-split h) ----
__global__ __launch_bounds__(256) void gemm2_k(
    const unsigned short* __restrict__ hhi, const unsigned short* __restrict__ hlo,
    const unsigned short* __restrict__ wgt_hi, const unsigned short* __restrict__ wgt_lo,
    unsigned short* __restrict__ gbf) {
  gemm_body64(blockIdx.x % G1_BX, blockIdx.x / G1_BX,
              hhi, hlo, wgt_hi, wgt_lo, gbf, N_NODES, HOUT);
}

// ---- scan stage 1: per-block sums ----
__global__ __launch_bounds__(256) void k_s1(const int* __restrict__ deg,
                                            int* __restrict__ bsum) {
  __shared__ int ss[256];
  int t = threadIdx.x;
  int i = blockIdx.x * 256 + t;
  ss[t] = (i < N_NODES) ? deg[i] : 0;
  __syncthreads();
  for (int d = 128; d > 0; d >>= 1) {
    if (t < d) ss[t] += ss[t + d];
    __syncthreads();
  }
  if (t == 0) bsum[blockIdx.x] = ss[0];
}

// ---- scan stage 2: exclusive scan of block sums ----
__global__ __launch_bounds__(256) void k_s2(const int* __restrict__ bsum,
                                            int* __restrict__ bbase,
                                            int* __restrict__ off) {
  __shared__ int ss[256];
  int t = threadIdx.x;
  int v = (t < NBLK) ? bsum[t] : 0;
  ss[t] = v;
  __syncthreads();
  for (int d = 1; d < 256; d <<= 1) {
    int u = (t >= d) ? ss[t - d] : 0;
    __syncthreads();
    ss[t] += u;
    __syncthreads();
  }
  if (t < NBLK) bbase[t] = ss[t] - v;
  if (t == NBLK - 1) off[N_NODES] = ss[t];
}

// ---- scan stage 3: block-local scan + base ----
__global__ __launch_bounds__(256) void k_s3(const int* __restrict__ deg,
                                            const int* __restrict__ bbase,
                                            int* __restrict__ off) {
  __shared__ int ss[256];
  int t = threadIdx.x;
  int i = blockIdx.x * 256 + t;
  int v = (i < N_NODES) ? deg[i] : 0;
  ss[t] = v;
  __syncthreads();
  for (int d = 1; d < 256; d <<= 1) {
    int u = (t >= d) ? ss[t - d] : 0;
    __syncthreads();
    ss[t] += u;
    __syncthreads();
  }
  if (i < N_NODES) off[i] = bbase[blockIdx.x] + ss[t] - v;
}

// ---- RGCN: gather from bf16 xt; wave/node; emits h (bf16 hi/lo) AND
//      attention coefficients a_s/a_d = h @ (W_gat @ att) ----
__global__ __launch_bounds__(256) void rgcn_gather(const unsigned short* __restrict__ xtbf,
                                                   const int* __restrict__ off,
                                                   const int* __restrict__ eprep,
                                                   const float* __restrict__ b_rgcn,
                                                   const float* __restrict__ was,
                                                   const float* __restrict__ wad,
                                                   unsigned short* __restrict__ hhi,
                                                   unsigned short* __restrict__ hlo,
                                                   float* __restrict__ a_s,
                                                   float* __restrict__ a_d) {
  int wid = (blockIdx.x * 256 + threadIdx.x) >> 6;
  int lane = threadIdx.x & 63;
  int half = lane >> 5;
  int cp = lane & 31;
  int start = off[wid], end = off[wid + 1];
  float a0x=0.f,a0y=0.f,a1x=0.f,a1y=0.f,a2x=0.f,a2y=0.f,a3x=0.f,a3y=0.f;
  int c0=0,c1=0,c2=0,c3=0;
  int niter = (end - start + 1) >> 1;
  for (int t = 0; t < niter; t += 2) {
    int idx0 = start + 2 * t + half;
    int idx1 = idx0 + 2;
    int p0 = (idx0 < end) ? eprep[idx0] : 0x70000;
    int p1 = (idx1 < end) ? eprep[idx1] : 0x70000;
    int s0 = p0 & 0xFFFF, r0 = p0 >> 16;
    int s1 = p1 & 0xFFFF, r1 = p1 >> 16;
    unsigned u0 = *reinterpret_cast<const unsigned*>(
        &xtbf[(size_t)s0 * MBIG + H1 + (r0 << 6) + cp * 2]);
    unsigned u1 = *reinterpret_cast<const unsigned*>(
        &xtbf[(size_t)s1 * MBIG + H1 + (r1 << 6) + cp * 2]);
    float v0x = bflo(u0), v0y = bfhi(u0);
    float v1x = bflo(u1), v1y = bfhi(u1);
    a0x += (r0==0)?v0x:0.f; a0y += (r0==0)?v0y:0.f; c0 += (r0==0);
    a1x += (r0==1)?v0x:0.f; a1y += (r0==1)?v0y:0.f; c1 += (r0==1);
    a2x += (r0==2)?v0x:0.f; a2y += (r0==2)?v0y:0.f; c2 += (r0==2);
    a3x += (r0==3)?v0x:0.f; a3y += (r0==3)?v0y:0.f; c3 += (r0==3);
    a0x += (r1==0)?v1x:0.f; a0y += (r1==0)?v1y:0.f; c0 += (r1==0);
    a1x += (r1==1)?v1x:0.f; a1y += (r1==1)?v1y:0.f; c1 += (r1==1);
    a2x += (r1==2)?v1x:0.f; a2y += (r1==2)?v1y:0.f; c2 += (r1==2);
    a3x += (r1==3)?v1x:0.f; a3y += (r1==3)?v1y:0.f; c3 += (r1==3);
  }
  a0x += __shfl_xor(a0x, 32); a0y += __shfl_xor(a0y, 32);
  a1x += __shfl_xor(a1x, 32); a1y += __shfl_xor(a1y, 32);
  a2x += __shfl_xor(a2x, 32); a2y += __shfl_xor(a2y, 32);
  a3x += __shfl_xor(a3x, 32); a3y += __shfl_xor(a3y, 32);
  c0 += __shfl_xor(c0, 32); c1 += __shfl_xor(c1, 32);
  c2 += __shfl_xor(c2, 32); c3 += __shfl_xor(c3, 32);
  if (half == 0) {
    unsigned ur = *reinterpret_cast<const unsigned*>(&xtbf[(size_t)wid * MBIG + cp * 2]);
    float2 bb = *reinterpret_cast<const float2*>(&b_rgcn[cp * 2]);
    float i0 = 1.0f / (float)max(c0, 1);
    float i1 = 1.0f / (float)max(c1, 1);
    float i2 = 1.0f / (float)max(c2, 1);
    float i3 = 1.0f / (float)max(c3, 1);
    float vx = bflo(ur) + bb.x + a0x * i0 + a1x * i1 + a2x * i2 + a3x * i3;
    float vy = bfhi(ur) + bb.y + a0y * i0 + a1y * i1 + a2y * i2 + a3y * i3;
    vx = fmaxf(vx, 0.f);
    vy = fmaxf(vy, 0.f);
    unsigned short hx = f2bf(vx), hy = f2bf(vy);
    ushort2 hv = {hx, hy};
    ushort2 lv = {f2bf(vx - bf2f(hx)), f2bf(vy - bf2f(hy))};
    *reinterpret_cast<ushort2*>(&hhi[(size_t)wid * H1 + cp * 2]) = hv;
    *reinterpret_cast<ushort2*>(&hlo[(size_t)wid * H1 + cp * 2]) = lv;
    // ---- fused attention coefficients: a = h @ was / h @ wad ----
    float4 wsA = *reinterpret_cast<const float4*>(&was[cp * 8]);      // k=2cp
    float4 wsB = *reinterpret_cast<const float4*>(&was[cp * 8 + 4]);  // k=2cp+1
    float4 wdA = *reinterpret_cast<const float4*>(&wad[cp * 8]);
    float4 wdB = *reinterpret_cast<const float4*>(&wad[cp * 8 + 4]);
    float ps0 = vx * wsA.x + vy * wsB.x;
    float ps1 = vx * wsA.y + vy * wsB.y;
    float ps2 = vx * wsA.z + vy * wsB.z;
    float ps3 = vx * wsA.w + vy * wsB.w;
    float pd0 = vx * wdA.x + vy * wdB.x;
    float pd1 = vx * wdA.y + vy * wdB.y;
    float pd2 = vx * wdA.z + vy * wdB.z;
    float pd3 = vx * wdA.w + vy * wdB.w;
#pragma unroll
    for (int d = 1; d < 32; d <<= 1) {
      ps0 += __shfl_xor(ps0, d); ps1 += __shfl_xor(ps1, d);
      ps2 += __shfl_xor(ps2, d); ps3 += __shfl_xor(ps3, d);
      pd0 += __shfl_xor(pd0, d); pd1 += __shfl_xor(pd1, d);
      pd2 += __shfl_xor(pd2, d); pd3 += __shfl_xor(pd3, d);
    }
    if (cp == 0) {
      *reinterpret_cast<float4*>(&a_s[(size_t)wid * 4]) = make_float4(ps0, ps1, ps2, ps3);
      *reinterpret_cast<float4*>(&a_d[(size_t)wid * 4]) = make_float4(pd0, pd1, pd2, pd3);
    }
  }
}

// ---- GAT + head fused ----
constexpr int GAT_BLOCKS = 2048;
constexpr int GAT_WAVES = GAT_BLOCKS * 4;   // 8192
__global__ __launch_bounds__(256) void gat_fused(const unsigned short* __restrict__ gbf,
                                                 const float* __restrict__ a_s,
                                                 const float* __restrict__ a_d,
                                                 const int* __restrict__ off,
                                                 const int* __restrict__ eprep,
                                                 const float* __restrict__ b_gat,
                                                 const float* __restrict__ W1,
                                                 const float* __restrict__ b1,
                                                 const int* __restrict__ batch,
                                                 unsigned* __restrict__ p_mono) {
  __shared__ float w1s[HOUT * 16];        // W1[k][j]
  __shared__ float ob[4][HOUT];           // per-wave o row
  __shared__ unsigned sp[N_GRAPHS * 16];
  const int t = threadIdx.x;
  for (int i = t; i < HOUT * 16; i += 256) w1s[i] = W1[i];
  for (int i = t; i < N_GRAPHS * 16; i += 256) sp[i] = MONO_NEG_INF;
  __syncthreads();
  const int wv = t >> 6, lane = t & 63;
  const int hh = lane >> 4;
  const int jj = lane & 15, grp = lane >> 4;
  const int w = blockIdx.x * 4 + wv;
  const int q = N_NODES / GAT_WAVES;
  const int r = N_NODES % GAT_WAVES;
  const int nbeg = w * q + ((w < r) ? w : r);
  const int ncnt = q + ((w < r) ? 1 : 0);
  for (int wid = nbeg; wid < nbeg + ncnt; ++wid) {
    int start = off[wid], end = off[wid + 1];
    float4 ad4 = *reinterpret_cast<const float4*>(a_d + (size_t)wid * 4);
    float adh = (hh == 0) ? ad4.x : (hh == 1) ? ad4.y : (hh == 2) ? ad4.z : ad4.w;
    float ox = 0.f, oy = 0.f, den = 0.f;
    int i = start;
    for (; i + 4 <= end; i += 4) {
      int p0 = eprep[i], p1 = eprep[i + 1], p2 = eprep[i + 2], p3 = eprep[i + 3];
      int s0 = p0 & 0xFFFF, s1 = p1 & 0xFFFF, s2 = p2 & 0xFFFF, s3 = p3 & 0xFFFF;
      float as0 = a_s[(size_t)s0 * 4 + hh];
      float as1 = a_s[(size_t)s1 * 4 + hh];
      float as2 = a_s[(size_t)s2 * 4 + hh];
      float as3 = a_s[(size_t)s3 * 4 + hh];
      unsigned u0 = *reinterpret_cast<const unsigned*>(&gbf[(size_t)s0 * HOUT + lane * 2]);
      unsigned u1 = *reinterpret_cast<const unsigned*>(&gbf[(size_t)s1 * HOUT + lane * 2]);
      unsigned u2 = *reinterpret_cast<const unsigned*>(&gbf[(size_t)s2 * HOUT + lane * 2]);
      unsigned u3 = *reinterpret_cast<const unsigned*>(&gbf[(size_t)s3 * HOUT + lane * 2]);
      float e0 = as0 + adh; e0 = (e0 > 0.f) ? e0 : 0.2f * e0;
      float e1 = as1 + adh; e1 = (e1 > 0.f) ? e1 : 0.2f * e1;
      float e2 = as2 + adh; e2 = (e2 > 0.f) ? e2 : 0.2f * e2;
      float e3 = as3 + adh; e3 = (e3 > 0.f) ? e3 : 0.2f * e3;
      float x0 = __expf(e0), x1 = __expf(e1), x2 = __expf(e2), x3 = __expf(e3);
      den += x0 + x1 + x2 + x3;
      ox += x0 * bflo(u0) + x1 * bflo(u1) + x2 * bflo(u2) + x3 * bflo(u3);
      oy += x0 * bfhi(u0) + x1 * bfhi(u1) + x2 * bfhi(u2) + x3 * bfhi(u3);
    }
    for (; i < end; ++i) {
      int p = eprep[i];
      int s = p & 0xFFFF;
      float as = a_s[(size_t)s * 4 + hh];
      unsigned u = *reinterpret_cast<const unsigned*>(&gbf[(size_t)s * HOUT + lane * 2]);
      float e = as + adh; e = (e > 0.f) ? e : 0.2f * e;
      float ex = __expf(e);
      den += ex;
      ox += ex * bflo(u);
      oy += ex * bfhi(u);
    }
    float dinv = (den > 0.f) ? (1.0f / den) : 0.f;
    float2 bg = *reinterpret_cast<const float2*>(b_gat + lane * 2);
    float vx = ox * dinv + bg.x; vx = (vx > 0.f) ? vx : 0.01f * vx;
    float vy = oy * dinv + bg.y; vy = (vy > 0.f) ? vy : 0.01f * vy;
    *reinterpret_cast<float2*>(&ob[wv][lane * 2]) = make_float2(vx, vy);
    float acc = 0.f;
#pragma unroll 8
    for (int i2 = 0; i2 < 32; ++i2) {
      int c = grp + 4 * i2;
      acc += ob[wv][c] * w1s[c * 16 + jj];
    }
    acc += __shfl_xor(acc, 16);
    acc += __shfl_xor(acc, 32);
    float z = acc + b1[jj];
    z = (z > 0.f) ? z : 0.01f * z;
    int b = batch[wid];
    if (lane < 16) atomicMax(&sp[b * 16 + jj], f2mono(z));
  }
  __syncthreads();
  for (int i = t; i < N_GRAPHS * 16; i += 256) {
    unsigned v = sp[i];
    if (v != MONO_NEG_INF) atomicMax(p_mono + i, v);
  }
}

// ---- y = p @ W2 + b2 ----
__global__ void final_y(const unsigned* __restrict__ p_mono,
                        const float* __restrict__ W2,
                        const float* __restrict__ b2,
                        float* __restrict__ y) {
  int gr = threadIdx.x;
  if (gr >= N_GRAPHS) return;
  float acc = b2[0];
#pragma unroll
  for (int k = 0; k < 16; ++k) acc += mono2f(p_mono[gr * 16 + k]) * W2[k];
  y[gr] = acc;
}

extern "C" void kernel_launch(void* const* d_in, const int* in_sizes, int n_in,
                              void* d_out, int out_size, void* d_ws, size_t ws_size,
                              hipStream_t stream) {
  const float* x       = (const float*)d_in[0];
  const int*   eidx    = (const int*)d_in[1];
  const int*   etype   = (const int*)d_in[2];
  const int*   batch   = (const int*)d_in[3];
  const float* W_rel   = (const float*)d_in[4];
  const float* W_root  = (const float*)d_in[5];
  const float* b_rgcn  = (const float*)d_in[6];
  const float* W_gat   = (const float*)d_in[7];
  const float* att_src = (const float*)d_in[8];
  const float* att_dst = (const float*)d_in[9];
  const float* b_gat   = (const float*)d_in[10];
  const float* W1      = (const float*)d_in[11];
  const float* b1      = (const float*)d_in[12];
  const float* W2      = (const float*)d_in[13];
  const float* b2      = (const float*)d_in[14];
  float* y = (float*)d_out;

  const int* src = eidx;
  const int* dst = eidx + N_EDGES;

  float* ws = (float*)d_ws;
  // ---- workspace layout (float offsets) ----
  const size_t OFF_XTBF= 0;           //  8,007,680 f: xt bf16 [N_PAD,320]
  const size_t OFF_GBF = 0;           //  g bf16 [N_PAD,128] (reuses xtbf)
  const size_t OFF_HHI = 8007680;     //  1,601,536 f: h hi bf16 [N_PAD,64]
  const size_t OFF_HLO = 9609216;     //  1,601,536 f: h lo
  const size_t OFF_AS  = 11210752;    //    200,000  a_src
  const size_t OFF_AD  = 11410752;    //    200,000  a_dst
  const size_t OFF_PM  = 11610752;    //      1,024 f = 1024 u32 pool max
  const size_t OFF_DEG = 11611776;    //     50,000  deg (int)
  const size_t OFF_OFFS= 11661776;    //     50,001  off (int)
  const size_t OFF_RANK= 11711780;    //    800,000  rank (int)
  const size_t OFF_EP  = 12511780;    //    800,000  eprep (int)
  const size_t OFF_BS  = 13311780;    //        196
  const size_t OFF_BB  = 13311976;    //        196
  const size_t OFF_WAS = 13312176;    //        256  was (16B aligned)
  const size_t OFF_WAD = 13312432;    //        256  wad
  const size_t OFF_WBH = 13312688;    //     20,480  WbigT_hi (16B aligned)
  const size_t OFF_WBL = 13333168;    //     20,480  WbigT_lo
  const size_t OFF_WGH = 13353648;    //      4,096  WgatT_hi
  const size_t OFF_WGL = 13357744;    //      4,096  WgatT_lo
  const size_t TOTAL_F = 13361840;
  if (ws_size < TOTAL_F * sizeof(float)) return;

  unsigned short* xtbf = (unsigned short*)(ws + OFF_XTBF);
  unsigned short* gbf  = (unsigned short*)(ws + OFF_GBF);
  unsigned short* hhi  = (unsigned short*)(ws + OFF_HHI);
  unsigned short* hlo  = (unsigned short*)(ws + OFF_HLO);
  float* a_s   = ws + OFF_AS;
  float* a_d   = ws + OFF_AD;
  unsigned* pm = (unsigned*)(ws + OFF_PM);
  int* deg     = (int*)(ws + OFF_DEG);
  int* offs    = (int*)(ws + OFF_OFFS);
  int* rank    = (int*)(ws + OFF_RANK);
  int* eprep   = (int*)(ws + OFF_EP);
  int* bsum    = (int*)(ws + OFF_BS);
  int* bbase   = (int*)(ws + OFF_BB);
  float* was   = ws + OFF_WAS;
  float* wad   = ws + OFF_WAD;
  unsigned short* wbt_hi = (unsigned short*)(ws + OFF_WBH);
  unsigned short* wbt_lo = (unsigned short*)(ws + OFF_WBL);
  unsigned short* wgt_hi = (unsigned short*)(ws + OFF_WGH);
  unsigned short* wgt_lo = (unsigned short*)(ws + OFF_WGL);

  // 1. deg = 0 (before fused hist)
  hipMemsetAsync(deg, 0, N_NODES * sizeof(int), stream);

  // 2. fused prep: hist(+rank) | build_wT | init_mono | watt
  pre_fused<<<HIST_BLOCKS + WT_BLOCKS + 2, 256, 0, stream>>>(
      W_root, W_rel, W_gat, att_src, att_dst, dst,
      wbt_hi, wbt_lo, wgt_hi, wgt_lo, deg, rank, pm, was, wad);

  // 3. scan (off from deg)
  k_s1<<<NBLK, 256, 0, stream>>>(deg, bsum);
  k_s2<<<1, 256, 0, stream>>>(bsum, bbase, offs);
  k_s3<<<NBLK, 256, 0, stream>>>(deg, bbase, offs);

  // 4. gemm1 (XCD-swizzled, async dbuf chunks) fused with CSR fill
  gemm1_fill<<<G1_GRID + HIST_BLOCKS, 256, 0, stream>>>(
      x, wbt_hi, wbt_lo, xtbf, src, dst, etype, offs, rank, eprep);

  // 5. RGCN gather -> h (bf16 hi/lo) + fused a_s/a_d
  rgcn_gather<<<N_NODES / 4, 256, 0, stream>>>(xtbf, offs, eprep, b_rgcn,
                                               was, wad, hhi, hlo, a_s, a_d);

  // 6. g = h @ W_gat
  gemm2_k<<<G1_BX * (HOUT / 64), 256, 0, stream>>>(hhi, hlo, wgt_hi, wgt_lo, gbf);

  // 7. fused GAT aggregation + head + per-graph max pool
  gat_fused<<<GAT_BLOCKS, 256, 0, stream>>>(gbf, a_s, a_d, offs, eprep, b_gat,
                                            W1, b1, batch, pm);

  // 8. y = p @ W2 + b2
  final_y<<<1, 64, 0, stream>>>(pm, W2, b2, y);
}